// Round 3
// baseline (434.245 us; speedup 1.0000x reference)
//
#include <hip/hip_runtime.h>
#include <hip/hip_bf16.h>

typedef unsigned short u16;
typedef unsigned int   u32;

#define B_  16
#define N_  5000
#define F_  512
#define C_  64
#define FC_ 128
#define NT  (B_ * N_)   // 80000 total nodes

__device__ __forceinline__ float bf2f(u16 h) {
    return __uint_as_float(((u32)h) << 16);
}
__device__ __forceinline__ u16 f2bf(float f) {
    union { __hip_bfloat16 h; u16 s; } c; c.h = __float2bfloat16(f); return c.s;
}
// dtype-flexible scalar weight load (fF: 1 = bf16 data, 0 = fp32 data)
__device__ __forceinline__ float ldw(const void* p, int i, int fF) {
    return fF ? bf2f(((const u16*)p)[i]) : ((const float*)p)[i];
}

// ---------------------------------------------------------------------------
// Detector: flags[0] = 1 if float tensors are bf16 (else fp32)
//           flags[1] = 1 if edge_index is int64 (else int32)
// bf16 test: low u16 of each u32 word of node_features. For bf16 data this is
// a bf16 of an N(0,1) value -> exponent field in [112,136] ~always. For fp32
// data it is random mantissa bits -> ~10% in range. 256 samples, threshold 128.
// int64 test: hi-words (odd u32 positions) of values < 5000 are all zero.
// ---------------------------------------------------------------------------
__global__ __launch_bounds__(256) void det_k(const u32* __restrict__ x32,
                                             const u32* __restrict__ ei32,
                                             int* __restrict__ flags)
{
    __shared__ int cnt;
    if (threadIdx.x == 0) cnt = 0;
    __syncthreads();
    u32 w = x32[threadIdx.x];
    int e = (int)((w >> 7) & 0xffu);          // exponent field of low-u16-as-bf16
    if (e >= 112 && e <= 136) atomicAdd(&cnt, 1);
    __syncthreads();
    if (threadIdx.x == 0) {
        flags[0] = (cnt >= 128) ? 1 : 0;
        u32 orv = 0;
        for (int i = 1; i < 64; i += 2) orv |= ei32[i];   // 32 odd words
        flags[1] = (orv == 0u) ? 1 : 0;
    }
}

// edge index accessors (ei32 = edge_index buffer viewed as u32)
__device__ __forceinline__ int src_at(const u32* ei32, int t, int E, int fI) {
    return (int)(fI ? ei32[2 * t] : ei32[t]);
}
__device__ __forceinline__ int dst_at(const u32* ei32, int t, int E, int fI) {
    return (int)(fI ? ei32[2 * (E + t)] : ei32[E + t]);
}

// ---------------------------------------------------------------------------
// Convert all small weights/biases -> fp32 in workspace.
// Element counts: W1 8192 | W2 256 | fc_w 16 | cw1 2048 | cw2 16 |
//                 b1 16 | b2 16 | fc_b 1 | cb1 16 | cb2 1   (total 10578)
// ---------------------------------------------------------------------------
__global__ __launch_bounds__(256) void prep_weights(
    const void* __restrict__ W1, const void* __restrict__ W2,
    const void* __restrict__ fcw, const void* __restrict__ cw1,
    const void* __restrict__ cw2, const void* __restrict__ b1,
    const void* __restrict__ b2, const void* __restrict__ fcb,
    const void* __restrict__ cb1, const void* __restrict__ cb2,
    const int* __restrict__ flags,
    float* __restrict__ w1f, float* __restrict__ w2f, float* __restrict__ fcwf,
    float* __restrict__ cw1f, float* __restrict__ cw2f, float* __restrict__ b1f,
    float* __restrict__ b2f, float* __restrict__ fcbf, float* __restrict__ cb1f,
    float* __restrict__ cb2f)
{
    int fF = flags[0];
    int t = blockIdx.x * blockDim.x + threadIdx.x;
    if (t < 8192) { w1f[t] = ldw(W1, t, fF); return; }
    int u = t - 8192;
    if (u < 256)  { w2f[u]  = ldw(W2, u, fF);  return; }  u -= 256;
    if (u < 16)   { fcwf[u] = ldw(fcw, u, fF); return; }  u -= 16;
    if (u < 2048) { cw1f[u] = ldw(cw1, u, fF); return; }  u -= 2048;
    if (u < 16)   { cw2f[u] = ldw(cw2, u, fF); return; }  u -= 16;
    if (u < 16)   { b1f[u]  = ldw(b1, u, fF);  return; }  u -= 16;
    if (u < 16)   { b2f[u]  = ldw(b2, u, fF);  return; }  u -= 16;
    if (u < 1)    { fcbf[u] = ldw(fcb, u, fF); return; }  u -= 1;
    if (u < 16)   { cb1f[u] = ldw(cb1, u, fF); return; }  u -= 16;
    if (u < 1)    { cb2f[u] = ldw(cb2, u, fF); return; }
}

// ---------------------------------------------------------------------------
// Degree count (graph shared across batch -> computed once). deg pre-zeroed.
// ---------------------------------------------------------------------------
__global__ __launch_bounds__(256) void deg_k(const u32* __restrict__ ei32,
                                             const int* __restrict__ flags,
                                             int* __restrict__ deg, int E)
{
    int t = blockIdx.x * blockDim.x + threadIdx.x;
    if (t >= E) return;
    int d = dst_at(ei32, t, E, flags[1]);
    if ((unsigned)d < (unsigned)N_) atomicAdd(&deg[d], 1);
}

// ---------------------------------------------------------------------------
// Single-block exclusive scan over deg[5000] -> rowptr/cursor, plus dinv.
// ---------------------------------------------------------------------------
__global__ __launch_bounds__(1024) void scan_k(const int* __restrict__ deg,
                                               int* __restrict__ rowptr,
                                               int* __restrict__ cursor,
                                               float* __restrict__ dinv)
{
    __shared__ int ssum[1024];
    int t = threadIdx.x;
    int base = t * 5;
    int loc[5];
    int run = 0;
#pragma unroll
    for (int i = 0; i < 5; i++) {
        int idx = base + i;
        int v = (idx < N_) ? deg[idx] : 0;
        loc[i] = run;
        run += v;
    }
    ssum[t] = run;
    __syncthreads();
    for (int offs = 1; offs < 1024; offs <<= 1) {
        int v = (t >= offs) ? ssum[t - offs] : 0;
        __syncthreads();
        ssum[t] += v;
        __syncthreads();
    }
    int exclusive = ssum[t] - run;
#pragma unroll
    for (int i = 0; i < 5; i++) {
        int idx = base + i;
        if (idx < N_) {
            int rp = exclusive + loc[i];
            rowptr[idx] = rp;
            cursor[idx] = rp;
            dinv[idx] = 1.0f / sqrtf((float)deg[idx] + 1.0f);  // +1 self loop
        }
    }
    if (t == 1023) rowptr[N_] = ssum[1023];
}

// ---------------------------------------------------------------------------
// CSR fill: csr[rowptr[d] ...] = list of src nodes with an edge into d.
// ---------------------------------------------------------------------------
__global__ __launch_bounds__(256) void fill_k(const u32* __restrict__ ei32,
                                              const int* __restrict__ flags,
                                              int* __restrict__ cursor,
                                              int* __restrict__ csr, int E)
{
    int t = blockIdx.x * blockDim.x + threadIdx.x;
    if (t >= E) return;
    int fI = flags[1];
    int s = src_at(ei32, t, E, fI);
    int d = dst_at(ei32, t, E, fI);
    if ((unsigned)d >= (unsigned)N_) return;
    if ((unsigned)s >= (unsigned)N_) s = 0;    // guard (only if detection wrong)
    int pos = atomicAdd(&cursor[d], 1);
    if ((unsigned)pos < (unsigned)E) csr[pos] = s;
}

// ---------------------------------------------------------------------------
// GEMM1: H'[b,n,k] = dinv[n] * sum_f x[b,n,f] * W1[f,k]  (80000x512 @ 512x16)
// One thread per node-row. W1 in fp32 -> wave-uniform s_loads. Output bf16.
// ---------------------------------------------------------------------------
__global__ __launch_bounds__(256) void gemm1_k(const void* __restrict__ xraw,
                                               const float* __restrict__ w1f,
                                               const float* __restrict__ dinv,
                                               const int* __restrict__ flags,
                                               u16* __restrict__ out)
{
    int row = blockIdx.x * blockDim.x + threadIdx.x;
    if (row >= NT) return;
    float acc[16];
#pragma unroll
    for (int k = 0; k < 16; k++) acc[k] = 0.0f;

    if (flags[0]) {   // bf16 input
        const u16* xr = (const u16*)xraw + (size_t)row * F_;
        for (int f = 0; f < F_; f += 8) {
            uint4 pk = *(const uint4*)(xr + f);
            u32 q[4] = {pk.x, pk.y, pk.z, pk.w};
#pragma unroll
            for (int j = 0; j < 4; j++) {
                float v0 = bf2f((u16)(q[j] & 0xffffu));
                float v1 = bf2f((u16)(q[j] >> 16));
                const float* w0 = w1f + (f + 2 * j) * 16;
#pragma unroll
                for (int k = 0; k < 16; k++) acc[k] += v0 * w0[k];
#pragma unroll
                for (int k = 0; k < 16; k++) acc[k] += v1 * w0[16 + k];
            }
        }
    } else {          // fp32 input
        const float* xr = (const float*)xraw + (size_t)row * F_;
        for (int f = 0; f < F_; f += 8) {
            float4 a = *(const float4*)(xr + f);
            float4 b = *(const float4*)(xr + f + 4);
            float v[8] = {a.x, a.y, a.z, a.w, b.x, b.y, b.z, b.w};
#pragma unroll
            for (int j = 0; j < 8; j++) {
                const float* w0 = w1f + (f + j) * 16;
#pragma unroll
                for (int k = 0; k < 16; k++) acc[k] += v[j] * w0[k];
            }
        }
    }
    float s = dinv[row % N_];
    union { uint4 u; u16 h[8]; } o0, o1;
#pragma unroll
    for (int k = 0; k < 8; k++) o0.h[k] = f2bf(acc[k] * s);
#pragma unroll
    for (int k = 0; k < 8; k++) o1.h[k] = f2bf(acc[8 + k] * s);
    uint4* op = (uint4*)(out + (size_t)row * 16);
    op[0] = o0.u;
    op[1] = o1.u;
}

// ---------------------------------------------------------------------------
// Aggregation 1: X1[b,d,k] = relu(dinv[d]*(H'[b,d,k] + sum_{s->d} H'[b,s,k]) + b1[k])
// 16 lanes per (b,d): lane k owns feature k -> each edge gather is one 32B read.
// ---------------------------------------------------------------------------
__global__ __launch_bounds__(256) void agg1_k(const u16* __restrict__ h,
                                              const int* __restrict__ rowptr,
                                              const int* __restrict__ csr,
                                              const float* __restrict__ dinv,
                                              const float* __restrict__ b1f,
                                              u16* __restrict__ out)
{
    int t = blockIdx.x * blockDim.x + threadIdx.x;
    int g = t >> 4;
    if (g >= NT) return;
    int k = t & 15;
    int d = g % N_;
    int b = g / N_;
    const u16* hb = h + (size_t)b * N_ * 16;
    float acc = bf2f(hb[d * 16 + k]);          // self loop (has dinv[d] already)
    int e0 = rowptr[d], e1 = rowptr[d + 1];
    for (int e = e0; e < e1; e++) {
        int s = csr[e];
        acc += bf2f(hb[s * 16 + k]);
    }
    float v = acc * dinv[d] + b1f[k];
    out[(size_t)g * 16 + k] = f2bf(fmaxf(v, 0.0f));
}

// ---------------------------------------------------------------------------
// GEMM2: H2'[b,n,k] = dinv[n] * sum_j X1[b,n,j] * W2[j,k]   (tiny 16x16)
// ---------------------------------------------------------------------------
__global__ __launch_bounds__(256) void gemm2_k(const u16* __restrict__ x1,
                                               const float* __restrict__ w2f,
                                               const float* __restrict__ dinv,
                                               u16* __restrict__ out)
{
    int row = blockIdx.x * blockDim.x + threadIdx.x;
    if (row >= NT) return;
    const uint4* xp = (const uint4*)(x1 + (size_t)row * 16);
    union { uint4 u; u16 h[8]; } i0, i1;
    i0.u = xp[0]; i1.u = xp[1];
    float xv[16];
#pragma unroll
    for (int j = 0; j < 8; j++) { xv[j] = bf2f(i0.h[j]); xv[8 + j] = bf2f(i1.h[j]); }
    float acc[16];
#pragma unroll
    for (int k = 0; k < 16; k++) acc[k] = 0.0f;
#pragma unroll
    for (int j = 0; j < 16; j++) {
        const float* wr = w2f + j * 16;
#pragma unroll
        for (int k = 0; k < 16; k++) acc[k] += xv[j] * wr[k];
    }
    float s = dinv[row % N_];
    union { uint4 u; u16 h[8]; } o0, o1;
#pragma unroll
    for (int k = 0; k < 8; k++) o0.h[k] = f2bf(acc[k] * s);
#pragma unroll
    for (int k = 0; k < 8; k++) o1.h[k] = f2bf(acc[8 + k] * s);
    uint4* op = (uint4*)(out + (size_t)row * 16);
    op[0] = o0.u;
    op[1] = o1.u;
}

// ---------------------------------------------------------------------------
// Aggregation 2 + fused node head:
//   x2[k] = relu(dinv[d]*(H2'[b,d,k] + sum_{s->d} H2'[b,s,k]) + b2[k])
//   nl[b,d] = sum_k x2[k]*fc_w[k] + fc_b      (16-lane shfl reduction)
// ---------------------------------------------------------------------------
__global__ __launch_bounds__(256) void agg2_k(const u16* __restrict__ h,
                                              const int* __restrict__ rowptr,
                                              const int* __restrict__ csr,
                                              const float* __restrict__ dinv,
                                              const float* __restrict__ b2f,
                                              const float* __restrict__ fcwf,
                                              const float* __restrict__ fcbf,
                                              float* __restrict__ nl)
{
    int t = blockIdx.x * blockDim.x + threadIdx.x;
    int g = t >> 4;
    if (g >= NT) return;
    int k = t & 15;
    int d = g % N_;
    int b = g / N_;
    const u16* hb = h + (size_t)b * N_ * 16;
    float acc = bf2f(hb[d * 16 + k]);
    int e0 = rowptr[d], e1 = rowptr[d + 1];
    for (int e = e0; e < e1; e++) {
        int s = csr[e];
        acc += bf2f(hb[s * 16 + k]);
    }
    float v = fmaxf(acc * dinv[d] + b2f[k], 0.0f);
    float p = v * fcwf[k];
    p += __shfl_xor(p, 8, 16);
    p += __shfl_xor(p, 4, 16);
    p += __shfl_xor(p, 2, 16);
    p += __shfl_xor(p, 1, 16);
    if (k == 0) nl[g] = p + fcbf[0];
}

// ---------------------------------------------------------------------------
// Column MLP: cl[b,c] = (relu(cf[b,c,:] @ cw1 + cb1)) @ cw2 + cb2
// ---------------------------------------------------------------------------
__global__ __launch_bounds__(256) void col_k(const void* __restrict__ cfraw,
                                             const float* __restrict__ cw1f,
                                             const float* __restrict__ cb1f,
                                             const float* __restrict__ cw2f,
                                             const float* __restrict__ cb2f,
                                             const int* __restrict__ flags,
                                             float* __restrict__ cl)
{
    int t = blockIdx.x * blockDim.x + threadIdx.x;
    if (t >= B_ * C_) return;
    float acc[16];
#pragma unroll
    for (int k = 0; k < 16; k++) acc[k] = cb1f[k];
    if (flags[0]) {
        const u16* r = (const u16*)cfraw + (size_t)t * FC_;
        for (int f = 0; f < FC_; f += 8) {
            uint4 pk = *(const uint4*)(r + f);
            u32 q[4] = {pk.x, pk.y, pk.z, pk.w};
#pragma unroll
            for (int j = 0; j < 4; j++) {
                float v0 = bf2f((u16)(q[j] & 0xffffu));
                float v1 = bf2f((u16)(q[j] >> 16));
                const float* w0 = cw1f + (f + 2 * j) * 16;
#pragma unroll
                for (int k = 0; k < 16; k++) acc[k] += v0 * w0[k];
#pragma unroll
                for (int k = 0; k < 16; k++) acc[k] += v1 * w0[16 + k];
            }
        }
    } else {
        const float* r = (const float*)cfraw + (size_t)t * FC_;
        for (int f = 0; f < FC_; f += 4) {
            float4 a = *(const float4*)(r + f);
            float v[4] = {a.x, a.y, a.z, a.w};
#pragma unroll
            for (int j = 0; j < 4; j++) {
                const float* w0 = cw1f + (f + j) * 16;
#pragma unroll
                for (int k = 0; k < 16; k++) acc[k] += v[j] * w0[k];
            }
        }
    }
    float s = cb2f[0];
#pragma unroll
    for (int k = 0; k < 16; k++) s += fmaxf(acc[k], 0.0f) * cw2f[k];
    cl[t] = s;
}

// ---------------------------------------------------------------------------
// Join: out[b, n*C + c] = nl[b,n] + cl[b,c]; output dtype follows input dtype
// (flags[0]: 1 -> bf16 out, 0 -> fp32 out). 8 elements per thread.
// ---------------------------------------------------------------------------
__global__ __launch_bounds__(256) void join_k(const float* __restrict__ nl,
                                              const float* __restrict__ cl,
                                              const int* __restrict__ flags,
                                              void* __restrict__ outraw)
{
    int t = blockIdx.x * blockDim.x + threadIdx.x;
    if (t >= NT * C_ / 8) return;
    int g  = t >> 3;          // b*N + n
    int c0 = (t & 7) * 8;
    int b  = g / N_;
    float nv = nl[g];
    const float* c = cl + b * C_ + c0;
    float4 a0 = *(const float4*)c;
    float4 a1 = *(const float4*)(c + 4);
    float v[8] = {a0.x, a0.y, a0.z, a0.w, a1.x, a1.y, a1.z, a1.w};
#pragma unroll
    for (int i = 0; i < 8; i++) v[i] += nv;
    size_t idx = (size_t)g * C_ + c0;
    if (flags[0]) {
        union { uint4 u; u16 h[8]; } pkv;
#pragma unroll
        for (int i = 0; i < 8; i++) pkv.h[i] = f2bf(v[i]);
        *(uint4*)((u16*)outraw + idx) = pkv.u;
    } else {
        float* o = (float*)outraw + idx;
        *(float4*)o       = make_float4(v[0], v[1], v[2], v[3]);
        *(float4*)(o + 4) = make_float4(v[4], v[5], v[6], v[7]);
    }
}

// ---------------------------------------------------------------------------
extern "C" void kernel_launch(void* const* d_in, const int* in_sizes, int n_in,
                              void* d_out, int out_size, void* d_ws, size_t ws_size,
                              hipStream_t stream)
{
    const void* x    = d_in[0];              // node_features  [B,N,F]
    const void* cf   = d_in[1];              // col_features   [B,C,FC]
    const u32*  ei32 = (const u32*)d_in[2];  // edge_index     [2,E] int32 or int64
    const void* W1   = d_in[3];
    const void* b1   = d_in[4];
    const void* W2   = d_in[5];
    const void* b2   = d_in[6];
    const void* fcw  = d_in[7];
    const void* fcb  = d_in[8];
    const void* cw1  = d_in[9];
    const void* cb1  = d_in[10];
    const void* cw2  = d_in[11];
    const void* cb2  = d_in[12];

    const int E = in_sizes[2] / 2;

    // workspace layout (~6.2 MB)
    char* base = (char*)d_ws;
    size_t off = 0;
    auto alloc = [&](size_t bytes) -> void* {
        void* p = base + off;
        off = (off + bytes + 255) & ~(size_t)255;
        return p;
    };
    int*   flags  = (int*)alloc(2 * 4);
    float* w1f  = (float*)alloc(8192 * 4);
    float* w2f  = (float*)alloc(256 * 4);
    float* fcwf = (float*)alloc(16 * 4);
    float* cw1f = (float*)alloc(2048 * 4);
    float* cw2f = (float*)alloc(16 * 4);
    float* b1f  = (float*)alloc(16 * 4);
    float* b2f  = (float*)alloc(16 * 4);
    float* fcbf = (float*)alloc(4);
    float* cb1f = (float*)alloc(16 * 4);
    float* cb2f = (float*)alloc(4);
    int*   deg    = (int*)alloc((size_t)N_ * 4);
    int*   rowptr = (int*)alloc((size_t)(N_ + 1) * 4);
    int*   cursor = (int*)alloc((size_t)N_ * 4);
    float* dinv   = (float*)alloc((size_t)N_ * 4);
    int*   csr    = (int*)alloc((size_t)E * 4);
    u16*   bufA = (u16*)alloc((size_t)NT * 16 * 2);   // H'  (bf16)
    u16*   bufB = (u16*)alloc((size_t)NT * 16 * 2);   // X1  (bf16)
    float* nl   = (float*)alloc((size_t)NT * 4);
    float* cl   = (float*)alloc((size_t)B_ * C_ * 4);

    det_k<<<1, 256, 0, stream>>>((const u32*)x, ei32, flags);
    hipMemsetAsync(deg, 0, (size_t)N_ * 4, stream);
    prep_weights<<<(10578 + 255) / 256, 256, 0, stream>>>(
        W1, W2, fcw, cw1, cw2, b1, b2, fcb, cb1, cb2, flags,
        w1f, w2f, fcwf, cw1f, cw2f, b1f, b2f, fcbf, cb1f, cb2f);
    deg_k<<<(E + 255) / 256, 256, 0, stream>>>(ei32, flags, deg, E);
    scan_k<<<1, 1024, 0, stream>>>(deg, rowptr, cursor, dinv);
    fill_k<<<(E + 255) / 256, 256, 0, stream>>>(ei32, flags, cursor, csr, E);

    gemm1_k<<<(NT + 255) / 256, 256, 0, stream>>>(x, w1f, dinv, flags, bufA);
    agg1_k<<<(NT * 16 + 255) / 256, 256, 0, stream>>>(bufA, rowptr, csr, dinv, b1f, bufB);
    gemm2_k<<<(NT + 255) / 256, 256, 0, stream>>>(bufB, w2f, dinv, bufA);
    agg2_k<<<(NT * 16 + 255) / 256, 256, 0, stream>>>(bufA, rowptr, csr, dinv, b2f, fcwf, fcbf, nl);
    col_k<<<(B_ * C_ + 255) / 256, 256, 0, stream>>>(cf, cw1f, cb1f, cw2f, cb2f, flags, cl);
    join_k<<<(NT * C_ / 8 + 255) / 256, 256, 0, stream>>>(nl, cl, flags, d_out);
}